// Round 5
// baseline (167.369 us; speedup 1.0000x reference)
//
#include <hip/hip_runtime.h>
#include <hip/hip_bf16.h>

#define M_DIM 4096
#define N_DIM 4096
#define K_DIM 4096
#define BM 256
#define BN 256
#define BK 64
#define NTILES (K_DIM / BK)   // 64

typedef __attribute__((ext_vector_type(8))) short short8;
typedef __attribute__((ext_vector_type(4))) float float4v;

__device__ __forceinline__ unsigned short f2bf(float f) {
    return __builtin_bit_cast(unsigned short, __float2bfloat16(f));
}

__device__ __forceinline__ void gload_lds16(const unsigned short* gsrc, unsigned short* lds) {
    __builtin_amdgcn_global_load_lds(
        (const __attribute__((address_space(1))) unsigned int*)gsrc,
        (__attribute__((address_space(3))) unsigned int*)lds,
        16, 0, 0);
}

// compiler fence + raw barrier (no vmcnt drain — vmcnt counted manually)
#define BAR() do { asm volatile("" ::: "memory"); __builtin_amdgcn_s_barrier(); \
                   asm volatile("" ::: "memory"); } while (0)

// 16-MFMA quadrant: compile-time acc offsets (rule #20: no runtime indexing)
#define MFMA_Q(AR, BR, MO, NO)                                                   \
  do {                                                                           \
    __builtin_amdgcn_s_setprio(1);                                               \
    _Pragma("unroll") for (int mf = 0; mf < 4; ++mf)                             \
      _Pragma("unroll") for (int nf = 0; nf < 2; ++nf)                           \
        _Pragma("unroll") for (int kk = 0; kk < 2; ++kk)                         \
          acc[(MO) + mf][(NO) + nf] = __builtin_amdgcn_mfma_f32_16x16x32_bf16(   \
              AR[mf][kk], BR[nf][kk], acc[(MO) + mf][(NO) + nf], 0, 0, 0);       \
    __builtin_amdgcn_s_setprio(0);                                               \
  } while (0)

// ---------------- fp32 -> bf16 conversion pass ----------------
__global__ __launch_bounds__(256)
void cvt_fp32_bf16(const float* __restrict__ X, const float* __restrict__ W,
                   unsigned short* __restrict__ XB, unsigned short* __restrict__ WB) {
    const long per_mat = (long)M_DIM * K_DIM / 8;
    const long total   = 2 * per_mat;
    for (long u = (long)blockIdx.x * blockDim.x + threadIdx.x; u < total;
         u += (long)gridDim.x * blockDim.x) {
        const float* src;
        unsigned short* dst;
        long v;
        if (u < per_mat) { src = X; dst = XB; v = u; }
        else             { src = W; dst = WB; v = u - per_mat; }
        float4v a = *(const float4v*)(src + v * 8);
        float4v b = *(const float4v*)(src + v * 8 + 4);
        short8 o;
#pragma unroll
        for (int e = 0; e < 4; ++e) {
            o[e]     = (short)f2bf(a[e]);
            o[e + 4] = (short)f2bf(b[e]);
        }
        *(short8*)(dst + v * 8) = o;
    }
}

// ---------------- 256x256 bf16 GEMM, one-barrier 4-phase pipeline ----------------
// LDS: 8 regions x 16KB = 128KB, fragment-major (zero-conflict ds_read_b128,
// verified round 4). Phase = {READS; STAGE; [vmcnt]; BAR; MFMA} — reads/stages of
// phase p+1 overlap other waves' MFMA(p) (single barrier per phase).
// WAR rule: stage in phase p only overwrites regions last read in phase <= p-2.
//   P1: stage B-rho1(t+1)->buf^1  (old readers: P3(t-1))
//   P2: stage B-rho0(t+1)->buf^1  (old readers: P3(t-1))
//   P3: stage A-rho0(t+2)->buf    (old reader:  P1(t))
//   P4: stage A-rho1(t+2)->buf    (old reader:  P2(t)); vmcnt(4) -> tile t+1 landed
__global__ __launch_bounds__(512, 2)
void gemm_8ph(const unsigned short* __restrict__ XB, const unsigned short* __restrict__ WB,
              const float* __restrict__ Bv, float* __restrict__ O) {
    extern __shared__ unsigned short lds[];

    const int tid  = threadIdx.x;
    const int lane = tid & 63;
    const int wid  = tid >> 6;
    const int wm   = wid >> 2;   // 0..1 (M half)
    const int wn   = wid & 3;    // 0..3 (N quarter)

    // bijective XCD swizzle (nwg=256, %8==0)
    const int wg   = (blockIdx.x & 7) * 32 + (blockIdx.x >> 3);
    const int brow = (wg >> 4) * BM;
    const int bcol = (wg & 15) * BN;

    // staging source (fragment-major): wave wid stages chunk wid of the rho-block;
    // lane l supplies row (wid>>1)*16 + (l&15), k (wid&1)*32 + (l>>4)*8
    const int srow_loc = (wid >> 1) * 16 + (lane & 15);
    const int skcol    = (wid & 1) * 32 + (lane >> 4) * 8;

    auto STAGE1 = [&](int mat, int half, int rho, int buf, int t) {
        const unsigned short* gsrc = (mat == 0)
            ? XB + (long)(brow + half * 128 + rho * 64 + srow_loc) * K_DIM + t * 64 + skcol
            : WB + (long)(bcol + half * 128 + rho * 64 + srow_loc) * K_DIM + t * 64 + skcol;
        unsigned short* reg = lds + (mat * 4 + half * 2 + buf) * 8192;
        gload_lds16(gsrc, reg + rho * 4096 + wid * 512);
    };

    auto LDA = [&](short8 (&dst)[4][2], int buf, int rho) {
        const unsigned short* base =
            lds + (wm * 2 + buf) * 8192 + rho * 4096 + lane * 8;
#pragma unroll
        for (int mf = 0; mf < 4; ++mf)
#pragma unroll
            for (int kk = 0; kk < 2; ++kk)
                dst[mf][kk] = *(const short8*)(base + (mf * 2 + kk) * 512);
    };
    auto LDB = [&](short8 (&dst)[2][2], int buf, int nh) {
        const unsigned short* base =
            lds + (4 + (wn >> 1) * 2 + buf) * 8192 + (wn & 1) * 4096 + lane * 8;
#pragma unroll
        for (int nf = 0; nf < 2; ++nf)
#pragma unroll
            for (int kk = 0; kk < 2; ++kk)
                dst[nf][kk] = *(const short8*)(base + ((nh * 2 + nf) * 2 + kk) * 512);
    };

    float4v acc[8][4] = {};
    short8 a0[4][2], a1[4][2], b0[2][2], b1[2][2];

    // ---- prologue: tile0 fully (8) + tile1's A (4) ----
    STAGE1(0, 0, 0, 0, 0); STAGE1(0, 1, 0, 0, 0);
    STAGE1(0, 0, 1, 0, 0); STAGE1(0, 1, 1, 0, 0);
    STAGE1(1, 0, 0, 0, 0); STAGE1(1, 1, 0, 0, 0);
    STAGE1(1, 0, 1, 0, 0); STAGE1(1, 1, 1, 0, 0);
    STAGE1(0, 0, 0, 1, 1); STAGE1(0, 1, 0, 1, 1);
    STAGE1(0, 0, 1, 1, 1); STAGE1(0, 1, 1, 1, 1);
    asm volatile("s_waitcnt vmcnt(4)" ::: "memory");  // tile0's 8 landed; A(1) in flight
    BAR();

    auto do_tile = [&](int buf, int t) {
        // P1: reads a0+b0; stage B-rho1(t+1)
        LDA(a0, buf, 0);
        LDB(b0, buf, 0);
        if (t + 1 < NTILES) { STAGE1(1, 0, 1, buf ^ 1, t + 1); STAGE1(1, 1, 1, buf ^ 1, t + 1); }
        BAR();
        MFMA_Q(a0, b0, 0, 0);
        // P2: reads a1; stage B-rho0(t+1)
        LDA(a1, buf, 1);
        if (t + 1 < NTILES) { STAGE1(1, 0, 0, buf ^ 1, t + 1); STAGE1(1, 1, 0, buf ^ 1, t + 1); }
        BAR();
        MFMA_Q(a1, b0, 4, 0);
        // P3: reads b1; stage A-rho0(t+2)
        LDB(b1, buf, 1);
        if (t + 2 < NTILES) { STAGE1(0, 0, 0, buf, t + 2); STAGE1(0, 1, 0, buf, t + 2); }
        BAR();
        MFMA_Q(a1, b1, 4, 2);
        // P4: no reads; stage A-rho1(t+2); counted vmcnt -> tile t+1 ready
        if (t + 2 < NTILES) { STAGE1(0, 0, 1, buf, t + 2); STAGE1(0, 1, 1, buf, t + 2); }
        if (t + 2 < NTILES) {
            asm volatile("s_waitcnt vmcnt(4)" ::: "memory");
        } else if (t + 1 < NTILES) {
            asm volatile("s_waitcnt vmcnt(0)" ::: "memory");
        }
        BAR();
        MFMA_Q(a0, b1, 0, 2);
    };

    for (int it = 0; it < NTILES / 2; ++it) {
        do_tile(0, 2 * it);
        do_tile(1, 2 * it + 1);
    }

    // ---- epilogue: bias + store (D: col = lane&15, row = (lane>>4)*4 + r) ----
#pragma unroll
    for (int nf = 0; nf < 4; ++nf) {
        const int col = bcol + wn * 64 + nf * 16 + (lane & 15);
        const float bias = Bv[col];
#pragma unroll
        for (int mf = 0; mf < 8; ++mf) {
            const int row0 = brow + wm * 128 + mf * 16 + (lane >> 4) * 4;
#pragma unroll
            for (int r = 0; r < 4; ++r)
                O[(long)(row0 + r) * N_DIM + col] = acc[mf][nf][r] + bias;
        }
    }
}

extern "C" void kernel_launch(void* const* d_in, const int* in_sizes, int n_in,
                              void* d_out, int out_size, void* d_ws, size_t ws_size,
                              hipStream_t stream) {
    const float* X  = (const float*)d_in[0];
    const float* W  = (const float*)d_in[1];
    const float* Bv = (const float*)d_in[2];
    float* O        = (float*)d_out;

    unsigned short* XB = (unsigned short*)d_ws;
    unsigned short* WB = XB + (size_t)M_DIM * K_DIM;

    hipFuncSetAttribute((const void*)gemm_8ph,
                        hipFuncAttributeMaxDynamicSharedMemorySize, 131072);

    hipLaunchKernelGGL(cvt_fp32_bf16, dim3(2048), dim3(256), 0, stream, X, W, XB, WB);
    hipLaunchKernelGGL(gemm_8ph, dim3((M_DIM / BM) * (N_DIM / BN)), dim3(512), 131072,
                       stream, XB, WB, Bv, O);
}

// Round 6
// 163.776 us; speedup vs baseline: 1.0219x; 1.0219x over previous
//
#include <hip/hip_runtime.h>
#include <hip/hip_bf16.h>

#define M_DIM 4096
#define N_DIM 4096
#define K_DIM 4096
#define BM 256
#define BN 256
#define BK 64
#define NTILES (K_DIM / BK)   // 64

typedef __attribute__((ext_vector_type(8))) short short8;
typedef __attribute__((ext_vector_type(4))) float float4v;

__device__ __forceinline__ unsigned short f2bf(float f) {
    return __builtin_bit_cast(unsigned short, __float2bfloat16(f));
}

__device__ __forceinline__ void gload_lds16(const unsigned short* gsrc, unsigned short* lds) {
    __builtin_amdgcn_global_load_lds(
        (const __attribute__((address_space(1))) unsigned int*)gsrc,
        (__attribute__((address_space(3))) unsigned int*)lds,
        16, 0, 0);
}

#define BAR() do { asm volatile("" ::: "memory"); __builtin_amdgcn_s_barrier(); \
                   asm volatile("" ::: "memory"); } while (0)

// 16 MFMA, kk OUTER so adjacent instructions are acc-independent
#define MFMA_Q(AR, BR, MO, NO)                                                   \
  do {                                                                           \
    __builtin_amdgcn_s_setprio(1);                                               \
    _Pragma("unroll") for (int kk = 0; kk < 2; ++kk)                             \
      _Pragma("unroll") for (int mf = 0; mf < 4; ++mf)                           \
        _Pragma("unroll") for (int nf = 0; nf < 2; ++nf)                         \
          acc[(MO) + mf][(NO) + nf] = __builtin_amdgcn_mfma_f32_16x16x32_bf16(   \
              AR[mf][kk], BR[nf][kk], acc[(MO) + mf][(NO) + nf], 0, 0, 0);       \
    __builtin_amdgcn_s_setprio(0);                                               \
  } while (0)

// ---------------- fp32 -> bf16 conversion pass ----------------
__global__ __launch_bounds__(256)
void cvt_fp32_bf16(const float* __restrict__ X, const float* __restrict__ W,
                   unsigned short* __restrict__ XB, unsigned short* __restrict__ WB) {
    const long per_mat = (long)M_DIM * K_DIM / 8;
    const long total   = 2 * per_mat;
    for (long u = (long)blockIdx.x * blockDim.x + threadIdx.x; u < total;
         u += (long)gridDim.x * blockDim.x) {
        const float* src;
        unsigned short* dst;
        long v;
        if (u < per_mat) { src = X; dst = XB; v = u; }
        else             { src = W; dst = WB; v = u - per_mat; }
        float4v a = *(const float4v*)(src + v * 8);
        float4v b = *(const float4v*)(src + v * 8 + 4);
        short8 o;
#pragma unroll
        for (int e = 0; e < 4; ++e) {
            o[e]     = (short)f2bf(a[e]);
            o[e + 4] = (short)f2bf(b[e]);
        }
        *(short8*)(dst + v * 8) = o;
    }
}

// ---------------- 256x256 bf16 GEMM, one-barrier 4-phase pipeline ----------------
// LDS: 8 regions x 16KB = 128KB. Region idx = mat*4 + half*2 + buf.
// Region = 2 rho-blocks of [64 rows][64 k] bf16, XOR-swizzled:
//   stored_byte(row,kb) = row*128 + (kb ^ ((row&7)<<4))
// Staged COARSE (wave wid -> rows wid*8..+8, one permuted 128B segment/row);
// read as b128 with per-lane swizzled base -> 2 lanes/bank (free, m136).
// Schedule per tile (1 barrier/phase, WAR gap >= 2 phases, vmcnt(4)/tile):
//   P1: stage B-rho1(t+1)->buf^1 | read a0,b0 | BAR | Q00
//   P2: stage B-rho0(t+1)->buf^1 | read a1    | BAR | Q10
//   P3: stage A-rho0(t+2)->buf   | read b1    | BAR | Q11
//   P4: stage A-rho1(t+2)->buf   | vmcnt(4)   | BAR | Q01
__global__ __launch_bounds__(512, 2)
void gemm_8ph(const unsigned short* __restrict__ XB, const unsigned short* __restrict__ WB,
              const float* __restrict__ Bv, float* __restrict__ O) {
    extern __shared__ unsigned short lds[];

    const int tid  = threadIdx.x;
    const int lane = tid & 63;
    const int wid  = tid >> 6;
    const int wm   = wid >> 2;   // 0..1 (M half)
    const int wn   = wid & 3;    // 0..3 (N quarter)

    // bijective XCD swizzle (nwg=256, %8==0)
    const int wg   = (blockIdx.x & 7) * 32 + (blockIdx.x >> 3);
    const int brow = (wg >> 4) * BM;
    const int bcol = (wg & 15) * BN;

    // staging: wave wid covers rows wid*8 + (lane>>3) of the rho-block;
    // lane's global k-chunk is the inverse-swizzled slot (lane&7)^(row&7)
    const int sgrow  = wid * 8 + (lane >> 3);
    const int skcol  = ((lane & 7) ^ ((lane >> 3) & 7)) * 8;   // shorts

    auto STAGE1 = [&](int mat, int half, int rho, int buf, int t) {
        const unsigned short* gsrc = (mat == 0)
            ? XB + (long)(brow + half * 128 + rho * 64 + sgrow) * K_DIM + t * 64 + skcol
            : WB + (long)(bcol + half * 128 + rho * 64 + sgrow) * K_DIM + t * 64 + skcol;
        unsigned short* reg = lds + (mat * 4 + half * 2 + buf) * 8192;
        gload_lds16(gsrc, reg + rho * 4096 + wid * 512);
    };

    // read addressing (shorts): row = f*16 + (lane&15); row&7 == lane&7
    const int rowoff = (lane & 15) * 64;
    const int kswz0  = ((((lane >> 4) * 16)      ^ ((lane & 7) << 4)) >> 1);
    const int kswz1  = (((64 + (lane >> 4) * 16) ^ ((lane & 7) << 4)) >> 1);

    auto LDA = [&](short8 (&dst)[4][2], int buf, int rho) {
        const unsigned short* base =
            lds + (wm * 2 + buf) * 8192 + rho * 4096 + rowoff;
#pragma unroll
        for (int mf = 0; mf < 4; ++mf) {
            dst[mf][0] = *(const short8*)(base + mf * 1024 + kswz0);
            dst[mf][1] = *(const short8*)(base + mf * 1024 + kswz1);
        }
    };
    auto LDB = [&](short8 (&dst)[2][2], int buf, int nh) {
        const unsigned short* base =
            lds + (4 + (wn >> 1) * 2 + buf) * 8192 + (wn & 1) * 4096 + nh * 2048 + rowoff;
#pragma unroll
        for (int nf = 0; nf < 2; ++nf) {
            dst[nf][0] = *(const short8*)(base + nf * 1024 + kswz0);
            dst[nf][1] = *(const short8*)(base + nf * 1024 + kswz1);
        }
    };

    float4v acc[8][4] = {};
    short8 a0[4][2], a1[4][2], b0[2][2], b1[2][2];

    // ---- prologue: tile0 fully (8) + tile1's A (4) ----
    STAGE1(0, 0, 0, 0, 0); STAGE1(0, 1, 0, 0, 0);
    STAGE1(0, 0, 1, 0, 0); STAGE1(0, 1, 1, 0, 0);
    STAGE1(1, 0, 0, 0, 0); STAGE1(1, 1, 0, 0, 0);
    STAGE1(1, 0, 1, 0, 0); STAGE1(1, 1, 1, 0, 0);
    STAGE1(0, 0, 0, 1, 1); STAGE1(0, 1, 0, 1, 1);
    STAGE1(0, 0, 1, 1, 1); STAGE1(0, 1, 1, 1, 1);
    asm volatile("s_waitcnt vmcnt(4)" ::: "memory");  // tile0's 8 landed; A(1) in flight
    BAR();

    auto do_tile = [&](int buf, int t) {
        // P1: stage B-rho1(t+1); read a0,b0
        if (t + 1 < NTILES) { STAGE1(1, 0, 1, buf ^ 1, t + 1); STAGE1(1, 1, 1, buf ^ 1, t + 1); }
        LDA(a0, buf, 0);
        LDB(b0, buf, 0);
        BAR();
        MFMA_Q(a0, b0, 0, 0);
        // P2: stage B-rho0(t+1); read a1
        if (t + 1 < NTILES) { STAGE1(1, 0, 0, buf ^ 1, t + 1); STAGE1(1, 1, 0, buf ^ 1, t + 1); }
        LDA(a1, buf, 1);
        BAR();
        MFMA_Q(a1, b0, 4, 0);
        // P3: stage A-rho0(t+2); read b1
        if (t + 2 < NTILES) { STAGE1(0, 0, 0, buf, t + 2); STAGE1(0, 1, 0, buf, t + 2); }
        LDB(b1, buf, 1);
        BAR();
        MFMA_Q(a1, b1, 4, 2);
        // P4: stage A-rho1(t+2); counted vmcnt -> tile t+1 fully landed
        if (t + 2 < NTILES) { STAGE1(0, 0, 1, buf, t + 2); STAGE1(0, 1, 1, buf, t + 2); }
        if (t + 2 < NTILES) {
            asm volatile("s_waitcnt vmcnt(4)" ::: "memory");
        } else if (t + 1 < NTILES) {
            asm volatile("s_waitcnt vmcnt(0)" ::: "memory");
        }
        BAR();
        MFMA_Q(a0, b1, 0, 2);
    };

    for (int it = 0; it < NTILES / 2; ++it) {
        do_tile(0, 2 * it);
        do_tile(1, 2 * it + 1);
    }

    // ---- epilogue: bias + store (D: col = lane&15, row = (lane>>4)*4 + r) ----
#pragma unroll
    for (int nf = 0; nf < 4; ++nf) {
        const int col = bcol + wn * 64 + nf * 16 + (lane & 15);
        const float bias = Bv[col];
#pragma unroll
        for (int mf = 0; mf < 8; ++mf) {
            const int row0 = brow + wm * 128 + mf * 16 + (lane >> 4) * 4;
#pragma unroll
            for (int r = 0; r < 4; ++r)
                O[(long)(row0 + r) * N_DIM + col] = acc[mf][nf][r] + bias;
        }
    }
}

extern "C" void kernel_launch(void* const* d_in, const int* in_sizes, int n_in,
                              void* d_out, int out_size, void* d_ws, size_t ws_size,
                              hipStream_t stream) {
    const float* X  = (const float*)d_in[0];
    const float* W  = (const float*)d_in[1];
    const float* Bv = (const float*)d_in[2];
    float* O        = (float*)d_out;

    unsigned short* XB = (unsigned short*)d_ws;
    unsigned short* WB = XB + (size_t)M_DIM * K_DIM;

    hipFuncSetAttribute((const void*)gemm_8ph,
                        hipFuncAttributeMaxDynamicSharedMemorySize, 131072);

    hipLaunchKernelGGL(cvt_fp32_bf16, dim3(2048), dim3(256), 0, stream, X, W, XB, WB);
    hipLaunchKernelGGL(gemm_8ph, dim3((M_DIM / BM) * (N_DIM / BN)), dim3(512), 131072,
                       stream, XB, WB, Bv, O);
}